// Round 7
// baseline (2964.232 us; speedup 1.0000x reference)
//
#include <hip/hip_runtime.h>
#include <hip/hip_bf16.h>

// DirectionalConvLayer on MI355X — MFMA + DPP-stats, 16-wave channel-split.
// x (8,64,256,256) f32, W (64,64,3,3) OIHW f32, b (64) f32.
// Height-1 rows with vpad 1 => width-3 1D conv using W[:,:,1,:] only.
// f[i] = elu(instnorm(conv(f[i-1]))) + x[i] forward; same backward over f.
// Bias omitted: InstanceNorm (no affine) exactly cancels per-channel shifts.
//
// One block per n (8 blocks). 1024 threads = 16 waves, split into 2
// channel-groups (waves 0-7 -> out ch 0-31, waves 8-15 -> ch 32-63);
// each wave covers 32 w-cols as before. Per-SIMD work per row is
// IDENTICAL to the 8-wave version (MFMA, stats trees, epilogue all same),
// but 4 waves/SIMD instead of 2 hide the DPP-chain bubbles / LDS latency /
// waitcnt stalls that were ~45% of the row. wA halves to 48 VGPR/lane so
// the 128-VGPR cap for 4 waves/EU has headroom. B-frag ds_reads are
// duplicated across groups (acceptable: LDS has slack).
//
// NOTE (rounds 1-2 lesson): keep round-0 64-bit inline load/store indexing —
// a uniform-base + byte-offset rewrite caused a pure-stall 2.25x regression.
// Stats: per-(mt,r) DPP row_shr add-trees -> lane 15 holds each 16-lane
// w-sum; cross-wave reduce lane<4, 4 channels/wave over its group's 8
// partials. Normalize via single fmaf (sNMR = -mean*rstd).
//
// (Round-6 bench was an infra failure — container acquisition, same error
// signature as rounds 3-4 which passed unchanged on retry; identical kernel
// resubmitted.)

#define CC 64
#define HH 256
#define WW 256
#define PITCH 72  // bf16 elems per sFT row (144 B, 16B-aligned)

typedef short bf16x8 __attribute__((ext_vector_type(8)));
typedef short bf16x4 __attribute__((ext_vector_type(4)));
typedef float f32x4  __attribute__((ext_vector_type(4)));

// Tree-sum within each 16-lane row via DPP row_shr; lane 15 of the row holds
// the full 16-lane sum on return (other lanes hold partials).
__device__ __forceinline__ float row16_sum_tail(float v) {
    float acc = v;
    int s;
    s = __builtin_amdgcn_update_dpp(0, __builtin_bit_cast(int, acc), 0x111, 0xF, 0xF, true);
    acc += __builtin_bit_cast(float, s);
    s = __builtin_amdgcn_update_dpp(0, __builtin_bit_cast(int, acc), 0x112, 0xF, 0xF, true);
    acc += __builtin_bit_cast(float, s);
    s = __builtin_amdgcn_update_dpp(0, __builtin_bit_cast(int, acc), 0x114, 0xF, 0xF, true);
    acc += __builtin_bit_cast(float, s);
    s = __builtin_amdgcn_update_dpp(0, __builtin_bit_cast(int, acc), 0x118, 0xF, 0xF, true);
    acc += __builtin_bit_cast(float, s);
    return acc;
}

__global__ __launch_bounds__(1024, 4) void dirconv_mfma(
    const float* __restrict__ x,
    const float* __restrict__ Wt,
    const float* __restrict__ bias,
    float* out)
{
    const int n    = blockIdx.x;
    const int t    = threadIdx.x;
    const int wave = t >> 6;        // 0..15
    const int g    = wave >> 3;     // channel group: 0 -> ch 0-31, 1 -> ch 32-63
    const int wv   = wave & 7;      // w-position within group
    const int lane = t & 63;
    const int quad = lane >> 4;
    const int l16  = lane & 15;
    const int w0   = wv * 32;
    const int ob   = g * 32;        // output-channel base for this group

    __shared__ __hip_bfloat16 sFT[258 * PITCH];   // [w+1][i], pads at 0 and 257
    __shared__ float sRedS[16][CC];
    __shared__ float sRedQ[16][CC];
    __shared__ float sNMR[CC];    // -mean * rstd
    __shared__ float sRstd[CC];

    // ---- stage conv weights (middle kernel row) via LDS scratch (reuse sFT) ----
    __hip_bfloat16* sWs = sFT;  // [kw][i][o]
    for (int idx = t; idx < CC * CC * 9; idx += 1024) {
        int o = idx / 576; int rem = idx - o * 576;
        int i = rem / 9;   int p   = rem - i * 9;
        if (p >= 3 && p < 6)
            sWs[((p - 3) * CC + i) * CC + o] = __float2bfloat16(Wt[idx]);
    }
    __syncthreads();

    // A frags: wA[mt][kw][q], elem j = W[o = ob + mt*16 + l16][i = q*32+quad*8+j]
    bf16x8 wA[2][3][2];
    for (int mt = 0; mt < 2; mt++)
        for (int kw = 0; kw < 3; kw++)
            for (int q = 0; q < 2; q++) {
                bf16x8 v;
                int o = ob + mt * 16 + l16;
                #pragma unroll
                for (int j = 0; j < 8; j++) {
                    int i = q * 32 + quad * 8 + j;
                    v[j] = ((short*)sWs)[(kw * CC + i) * CC + o];
                }
                wA[mt][kw][q] = v;
            }
    __syncthreads();

    // ---- init: f0 = x row 0 -> sFT (bf16) and out (f32); zero pads ----
    const size_t nbase = (size_t)n * CC * HH * WW;
    for (int idx = t; idx < CC * WW; idx += 1024) {
        int c = idx >> 8, w = idx & 255;
        float v = x[nbase + (size_t)c * (HH * WW) + w];
        sFT[(w + 1) * PITCH + c] = __float2bfloat16(v);
        out[nbase + (size_t)c * (HH * WW) + w] = v;
    }
    if (t < CC) {
        sFT[0 * PITCH + t]   = __float2bfloat16(0.f);
        sFT[257 * PITCH + t] = __float2bfloat16(0.f);
    }
    __syncthreads();

    for (int phase = 0; phase < 2; phase++) {
        const float* src = (phase == 0) ? x : out;
        int row  = (phase == 0) ? 1 : HH - 2;
        int rend = (phase == 0) ? HH : -1;
        int rinc = (phase == 0) ? 1 : -1;

        for (; row != rend; row += rinc) {
            const size_t rowbase = nbase + (size_t)row * WW;

            // ---- prefetch src row (consumed in epilogue; hidden by conv) ----
            float srcv[2][2][4];
            #pragma unroll
            for (int nt = 0; nt < 2; nt++) {
                int w = w0 + nt * 16 + l16;
                #pragma unroll
                for (int mt = 0; mt < 2; mt++)
                    #pragma unroll
                    for (int r = 0; r < 4; r++) {
                        int o = ob + mt * 16 + quad * 4 + r;
                        srcv[nt][mt][r] = src[rowbase + (size_t)o * (HH * WW) + w];
                    }
            }

            // ---- conv via MFMA ----
            f32x4 acc[2][2];
            #pragma unroll
            for (int nt = 0; nt < 2; nt++)
                #pragma unroll
                for (int mt = 0; mt < 2; mt++)
                    acc[nt][mt] = (f32x4){0.f, 0.f, 0.f, 0.f};

            #pragma unroll
            for (int nt = 0; nt < 2; nt++) {
                int wr = w0 + nt * 16 + l16;
                #pragma unroll
                for (int kw = 0; kw < 3; kw++) {
                    const __hip_bfloat16* rp = &sFT[(wr + kw) * PITCH];
                    #pragma unroll
                    for (int q = 0; q < 2; q++) {
                        bf16x8 bf = *(const bf16x8*)(rp + q * 32 + quad * 8);
                        #pragma unroll
                        for (int mt = 0; mt < 2; mt++)
                            acc[nt][mt] = __builtin_amdgcn_mfma_f32_16x16x32_bf16(
                                wA[mt][kw][q], bf, acc[nt][mt], 0, 0, 0);
                    }
                }
            }

            // ---- stats via DPP trees (no LDS port) ----
            float sv[2][4], qv[2][4];
            #pragma unroll
            for (int mt = 0; mt < 2; mt++)
                #pragma unroll
                for (int r = 0; r < 4; r++) {
                    float a0 = acc[0][mt][r], a1 = acc[1][mt][r];
                    sv[mt][r] = row16_sum_tail(a0 + a1);
                    qv[mt][r] = row16_sum_tail(fmaf(a0, a0, a1 * a1));
                }
            if (l16 == 15) {
                #pragma unroll
                for (int mt = 0; mt < 2; mt++) {
                    *(f32x4*)&sRedS[wave][ob + mt * 16 + quad * 4] =
                        (f32x4){sv[mt][0], sv[mt][1], sv[mt][2], sv[mt][3]};
                    *(f32x4*)&sRedQ[wave][ob + mt * 16 + quad * 4] =
                        (f32x4){qv[mt][0], qv[mt][1], qv[mt][2], qv[mt][3]};
                }
            }
            __syncthreads();

            // ---- cross-wave reduce: wave handles channels [4w, 4w+4);
            //      channel o's 8 partials live in waves [(o>>5)*8, +8) ----
            if (lane < 4) {
                int o  = wave * 4 + lane;
                int j0 = (o >> 5) * 8;
                float s8 = 0.f, q8 = 0.f;
                #pragma unroll
                for (int j = 0; j < 8; j++) {
                    s8 += sRedS[j0 + j][o];
                    q8 += sRedQ[j0 + j][o];
                }
                float m   = s8 * (1.f / 256.f);
                float var = fmaf(m, -m, q8 * (1.f / 256.f));
                float rs  = rsqrtf(var + 1e-5f);
                sRstd[o] = rs;
                sNMR[o]  = -m * rs;
            }
            __syncthreads();

            // ---- epilogue: y = fma(acc, rstd, nmr); elu; +src; sFT; defer out ----
            float fv[2][2][4];
            #pragma unroll
            for (int mt = 0; mt < 2; mt++) {
                f32x4 nm = *(const f32x4*)&sNMR[ob + mt * 16 + quad * 4];
                f32x4 rr = *(const f32x4*)&sRstd[ob + mt * 16 + quad * 4];
                #pragma unroll
                for (int nt = 0; nt < 2; nt++) {
                    int w = w0 + nt * 16 + l16;
                    bf16x4 pk;
                    #pragma unroll
                    for (int r = 0; r < 4; r++) {
                        float y = fmaf(acc[nt][mt][r], rr[r], nm[r]);
                        y = (y > 0.f) ? y : (__expf(y) - 1.f);
                        float f = y + srcv[nt][mt][r];
                        fv[nt][mt][r] = f;
                        union { __hip_bfloat16 h; short s; } cv;
                        cv.h = __float2bfloat16(f);
                        pk[r] = cv.s;
                    }
                    *(bf16x4*)&sFT[(w + 1) * PITCH + ob + mt * 16 + quad * 4] = pk;
                }
            }
            __syncthreads();

            // ---- global stores after the barrier: drain overlaps next conv ----
            #pragma unroll
            for (int nt = 0; nt < 2; nt++) {
                int w = w0 + nt * 16 + l16;
                #pragma unroll
                for (int mt = 0; mt < 2; mt++)
                    #pragma unroll
                    for (int r = 0; r < 4; r++) {
                        int o = ob + mt * 16 + quad * 4 + r;
                        out[rowbase + (size_t)o * (HH * WW) + w] = fv[nt][mt][r];
                    }
            }
        }
    }
}

extern "C" void kernel_launch(void* const* d_in, const int* in_sizes, int n_in,
                              void* d_out, int out_size, void* d_ws, size_t ws_size,
                              hipStream_t stream) {
    const float* x  = (const float*)d_in[0];
    const float* Wt = (const float*)d_in[1];
    const float* b  = (const float*)d_in[2];
    float* out = (float*)d_out;
    dirconv_mfma<<<8, 1024, 0, stream>>>(x, Wt, b, out);
}